// Round 5
// baseline (239.361 us; speedup 1.0000x reference)
//
#include <hip/hip_runtime.h>

// SGC: out = A_hat^2 (x W^T) + b,  A_hat = D^-1/2 (A+I) D^-1/2.
// g-carry trick: g = D^-1/2 h, so each hop is an UNWEIGHTED neighbor sum:
//   g0 = dinv .* (x W^T)
//   g1 = dinv^2 .* (g0 + sum_{dst=n} g0[src])
//   out = dinv .* (g1 + sum_{dst=n} g1[src]) + b
//
// CSR build without global scans or random 4B scatters:
//   bucket_k : chunked counting-sort of edges into 782 dst-buckets (128 nodes
//              each) -> contiguous per-(chunk,bucket) runs, 1 atomic per run.
//   regroup_k: per bucket, LDS histogram + scan + scatter -> per-node runs,
//              written back IN-PLACE (coalesced); meta[node] = {beg, cnt}.
// GEMM: W staged in LDS (transposed float4), 4 rows/wave/iter — R4's VGPR=40
//       showed the register-resident W got rematerialized as per-row cache
//       loads (~4500 cyc/row); LDS makes the schedule deterministic.
// Hops: one wave per node, register accumulation, 100k independent waves.
//
// ws: gcur[1024] | pairs/ent[1024*2048] (8MB, in-place) | meta int2[N] | g1[N*64]

#define DF 64
#define BSHIFT 7
#define BNODES 128                 // nodes per bucket
#define NBP 1024                   // padded bucket count (used: ceil(N/128)=782)
#define CAP 2048                   // entries per bucket region (avg 1279, +21 sigma)
#define CHUNK 8192                 // edges per binning chunk

// ---- init bucket cursors ----
__global__ __launch_bounds__(256) void zero_k(int* __restrict__ gcur) {
    int i = blockIdx.x * 256 + threadIdx.x;
    if (i < NBP) gcur[i] = i * CAP;
}

// ---- chunked counting-sort of edges into dst-buckets ----
__global__ __launch_bounds__(256) void bucket_k(const int* __restrict__ src,
                                                const int* __restrict__ dst,
                                                int* gcur,
                                                unsigned* __restrict__ pairs, int ne) {
    __shared__ int bcnt[NBP];
    __shared__ int bofs[NBP];      // exclusive offsets, then running cursor
    __shared__ int gshift[NBP];    // global_base - local_exclusive_base
    __shared__ int stmp[256];
    int t = threadIdx.x;
    int e0 = blockIdx.x * CHUNK;
    int ecnt = min(CHUNK, ne - e0);

    for (int b = t; b < NBP; b += 256) bcnt[b] = 0;
    __syncthreads();

    // pass 1: per-bucket counts
    for (int i = t; i < ecnt; i += 256) {
        int d = dst[e0 + i];
        atomicAdd(&bcnt[d >> BSHIFT], 1);
    }
    __syncthreads();

    // block-exclusive scan over NBP=1024 counts (thread t owns 4t..4t+3)
    int b4 = t * 4;
    int c0 = bcnt[b4], c1 = bcnt[b4 + 1], c2 = bcnt[b4 + 2], c3 = bcnt[b4 + 3];
    int tsum = c0 + c1 + c2 + c3;
    stmp[t] = tsum;
    __syncthreads();
    for (int off = 1; off < 256; off <<= 1) {
        int v = stmp[t];
        int u = (t >= off) ? stmp[t - off] : 0;
        __syncthreads();
        stmp[t] = v + u;
        __syncthreads();
    }
    int ex = stmp[t] - tsum;
    int e1 = ex + c0, e2 = e1 + c1, e3 = e2 + c2;
    bofs[b4] = ex; bofs[b4 + 1] = e1; bofs[b4 + 2] = e2; bofs[b4 + 3] = e3;
    if (c0 > 0) gshift[b4]     = atomicAdd(&gcur[b4],     c0) - ex;
    if (c1 > 0) gshift[b4 + 1] = atomicAdd(&gcur[b4 + 1], c1) - e1;
    if (c2 > 0) gshift[b4 + 2] = atomicAdd(&gcur[b4 + 2], c2) - e2;
    if (c3 > 0) gshift[b4 + 3] = atomicAdd(&gcur[b4 + 3], c3) - e3;
    __syncthreads();

    // pass 2: scatter packed entries (row7|src17) into contiguous runs
    for (int i = t; i < ecnt; i += 256) {
        int d = dst[e0 + i], s = src[e0 + i];
        int b = d >> BSHIFT;
        int lp = atomicAdd(&bofs[b], 1);
        pairs[gshift[b] + lp] = ((unsigned)(d & (BNODES - 1)) << 17) | (unsigned)s;
    }
}

// ---- per-bucket regroup: node-sorted entries (in-place) + meta{beg,cnt} ----
__global__ __launch_bounds__(256) void regroup_k(const int* __restrict__ gcur,
                                                 unsigned* pairs,   // in: packed, out: ent
                                                 int2* __restrict__ meta, int n) {
    __shared__ int hist[BNODES];
    __shared__ int cur[BNODES];
    __shared__ int stage[CAP];
    int t = threadIdx.x, b = blockIdx.x;
    int base = b * CAP;
    int size = min(gcur[b] - base, CAP);

    if (t < BNODES) hist[t] = 0;
    __syncthreads();

    for (int i = t; i < size; i += 256)
        atomicAdd(&hist[pairs[base + i] >> 17], 1);
    __syncthreads();

    int cnt = (t < BNODES) ? hist[t] : 0;
    // Hillis-Steele inclusive scan over hist[0..127]
    for (int off = 1; off < BNODES; off <<= 1) {
        int u = (t < BNODES && t >= off) ? hist[t - off] : 0;
        __syncthreads();
        if (t < BNODES) hist[t] += u;
        __syncthreads();
    }
    if (t < BNODES) {
        int ex = hist[t] - cnt;
        cur[t] = ex;
        int node = (b << BSHIFT) + t;
        if (node < n) meta[node] = make_int2(base + ex, cnt);
    }
    __syncthreads();

    // scatter into LDS stage grouped by node
    for (int i = t; i < size; i += 256) {
        unsigned p = pairs[base + i];
        int pos = atomicAdd(&cur[p >> 17], 1);
        stage[pos] = (int)(p & 0x1FFFF);
    }
    __syncthreads();

    // coalesced write-back over the same region (block exclusively owns it)
    for (int i = t; i < size; i += 256)
        pairs[base + i] = (unsigned)stage[i];
}

// ---- g0 = dinv .* (x W^T): W in LDS (transposed float4), 4 rows/wave ----
#define RL(h, k) __uint_as_float(__builtin_amdgcn_readlane(__float_as_uint(h), (k)))

__global__ __launch_bounds__(256) void gemm_xw(const float* __restrict__ x,
                                               const float* __restrict__ Wm,
                                               const int2* __restrict__ meta,
                                               float* __restrict__ g0, int nrows) {
    __shared__ float4 wt[16 * 64];   // wt[k4*64 + j] = {W[j][4k4 .. 4k4+3]}
    int t = threadIdx.x;
    const float4* W4 = (const float4*)Wm;
#pragma unroll
    for (int i = 0; i < 4; ++i) {
        int idx = t + i * 256;
        int k4 = idx >> 6, j = idx & 63;
        wt[idx] = W4[j * 16 + k4];   // 16KB once per block; L2-resident
    }
    __syncthreads();

    int lane = t & 63;
    int wave = (blockIdx.x * blockDim.x + t) >> 6;
    int nwaves = (gridDim.x * blockDim.x) >> 6;

    for (int r0 = wave * 4; r0 < nrows; r0 += nwaves * 4) {
        int r1 = min(r0 + 1, nrows - 1);
        int r2 = min(r0 + 2, nrows - 1);
        int r3 = min(r0 + 3, nrows - 1);
        float h0 = x[r0 * DF + lane];   // coalesced 256B per row
        float h1 = x[r1 * DF + lane];
        float h2 = x[r2 * DF + lane];
        float h3 = x[r3 * DF + lane];
        float a00 = 0.f, a01 = 0.f, a02 = 0.f, a03 = 0.f;
        float a10 = 0.f, a11 = 0.f, a12 = 0.f, a13 = 0.f;
        float a20 = 0.f, a21 = 0.f, a22 = 0.f, a23 = 0.f;
        float a30 = 0.f, a31 = 0.f, a32 = 0.f, a33 = 0.f;
#pragma unroll
        for (int k4 = 0; k4 < 16; ++k4) {
            float4 wv = wt[k4 * 64 + lane];   // ds_read_b128, conflict-free
            a00 = fmaf(RL(h0, 4 * k4 + 0), wv.x, a00);
            a01 = fmaf(RL(h0, 4 * k4 + 1), wv.y, a01);
            a02 = fmaf(RL(h0, 4 * k4 + 2), wv.z, a02);
            a03 = fmaf(RL(h0, 4 * k4 + 3), wv.w, a03);
            a10 = fmaf(RL(h1, 4 * k4 + 0), wv.x, a10);
            a11 = fmaf(RL(h1, 4 * k4 + 1), wv.y, a11);
            a12 = fmaf(RL(h1, 4 * k4 + 2), wv.z, a12);
            a13 = fmaf(RL(h1, 4 * k4 + 3), wv.w, a13);
            a20 = fmaf(RL(h2, 4 * k4 + 0), wv.x, a20);
            a21 = fmaf(RL(h2, 4 * k4 + 1), wv.y, a21);
            a22 = fmaf(RL(h2, 4 * k4 + 2), wv.z, a22);
            a23 = fmaf(RL(h2, 4 * k4 + 3), wv.w, a23);
            a30 = fmaf(RL(h3, 4 * k4 + 0), wv.x, a30);
            a31 = fmaf(RL(h3, 4 * k4 + 1), wv.y, a31);
            a32 = fmaf(RL(h3, 4 * k4 + 2), wv.z, a32);
            a33 = fmaf(RL(h3, 4 * k4 + 3), wv.w, a33);
        }
        float s0 = (a00 + a01) + (a02 + a03);
        float s1 = (a10 + a11) + (a12 + a13);
        float s2 = (a20 + a21) + (a22 + a23);
        float s3 = (a30 + a31) + (a32 + a33);
        float dv0 = rsqrtf((float)(1 + meta[r0].y));
        float dv1 = rsqrtf((float)(1 + meta[r1].y));
        float dv2 = rsqrtf((float)(1 + meta[r2].y));
        float dv3 = rsqrtf((float)(1 + meta[r3].y));
        g0[r0 * DF + lane] = dv0 * s0;
        if (r0 + 1 < nrows) g0[r1 * DF + lane] = dv1 * s1;
        if (r0 + 2 < nrows) g0[r2 * DF + lane] = dv2 * s2;
        if (r0 + 3 < nrows) g0[r3 * DF + lane] = dv3 * s3;
    }
}

// ---- gather hop: one wave per node, register accumulation, 8-deep ILP ----
// MODE 0: out = dinv^2*(self+acc)      MODE 1: out = dinv*(self+acc)+bias
template <int MODE>
__global__ __launch_bounds__(256) void gather_k(const int2* __restrict__ meta,
                                                const unsigned* __restrict__ ent,
                                                const float* __restrict__ gin,
                                                const float* __restrict__ bias,
                                                float* __restrict__ out, int n) {
    int lane = threadIdx.x & 63;
    int wid = (blockIdx.x * blockDim.x + threadIdx.x) >> 6;
    wid = __builtin_amdgcn_readfirstlane(wid);   // wave-uniform -> scalar loads
    if (wid >= n) return;

    int2 m = meta[wid];
    int beg = m.x, cnt = m.y;
    float dv = rsqrtf((float)(1 + cnt));

    float a0 = gin[wid * DF + lane];  // self-loop term
    float a1 = 0.f, a2 = 0.f, a3 = 0.f, a4 = 0.f, a5 = 0.f, a6 = 0.f, a7 = 0.f;

    int i = beg, end = beg + cnt;
    for (; i + 7 < end; i += 8) {     // 8 independent chains
        int s0 = ent[i + 0], s1 = ent[i + 1], s2 = ent[i + 2], s3 = ent[i + 3];
        int s4 = ent[i + 4], s5 = ent[i + 5], s6 = ent[i + 6], s7 = ent[i + 7];
        a0 += gin[s0 * DF + lane];
        a1 += gin[s1 * DF + lane];
        a2 += gin[s2 * DF + lane];
        a3 += gin[s3 * DF + lane];
        a4 += gin[s4 * DF + lane];
        a5 += gin[s5 * DF + lane];
        a6 += gin[s6 * DF + lane];
        a7 += gin[s7 * DF + lane];
    }
    for (; i + 3 < end; i += 4) {
        int s0 = ent[i + 0], s1 = ent[i + 1], s2 = ent[i + 2], s3 = ent[i + 3];
        a0 += gin[s0 * DF + lane];
        a1 += gin[s1 * DF + lane];
        a2 += gin[s2 * DF + lane];
        a3 += gin[s3 * DF + lane];
    }
    for (; i < end; ++i) a0 += gin[ent[i] * DF + lane];

    float acc = ((a0 + a1) + (a2 + a3)) + ((a4 + a5) + (a6 + a7));
    if (MODE == 0)
        out[wid * DF + lane] = dv * dv * acc;
    else
        out[wid * DF + lane] = fmaf(dv, acc, bias[lane]);
}

extern "C" void kernel_launch(void* const* d_in, const int* in_sizes, int n_in,
                              void* d_out, int out_size, void* d_ws, size_t ws_size,
                              hipStream_t stream) {
    const float* x  = (const float*)d_in[0];
    const int*   ei = (const int*)d_in[1];
    const float* Wm = (const float*)d_in[2];
    const float* b  = (const float*)d_in[3];

    const int N = in_sizes[0] / DF;   // 100000
    const int E = in_sizes[1] / 2;    // 1000000
    const int* src = ei;
    const int* dst = ei + E;

    int*      gcur  = (int*)d_ws;                    // NBP
    unsigned* pairs = (unsigned*)(gcur + NBP);       // NBP*CAP (8MB), becomes ent
    int2*     meta  = (int2*)(pairs + NBP * CAP);    // N
    float*    g1    = (float*)(meta + N);            // N*DF
    float*    g0    = (float*)d_out;                 // reuse output buffer

    int gC = (E + CHUNK - 1) / CHUNK;                // 123 chunks
    int NB = (N + BNODES - 1) / BNODES;              // 782 buckets
    int gG = (N * DF + 255) / 256;                   // one wave per node

    zero_k<<<4, 256, 0, stream>>>(gcur);
    bucket_k<<<gC, 256, 0, stream>>>(src, dst, gcur, pairs, E);
    regroup_k<<<NB, 256, 0, stream>>>(gcur, pairs, meta, N);
    gemm_xw<<<1024, 256, 0, stream>>>(x, Wm, meta, g0, N);
    gather_k<0><<<gG, 256, 0, stream>>>(meta, pairs, g0, nullptr, g1, N);
    gather_k<1><<<gG, 256, 0, stream>>>(meta, pairs, g1, b, g0, N);
}

// Round 7
// 216.111 us; speedup vs baseline: 1.1076x; 1.1076x over previous
//
#include <hip/hip_runtime.h>

// SGC: out = A_hat^2 (x W^T) + b,  A_hat = D^-1/2 (A+I) D^-1/2.
// g-carry trick: g = D^-1/2 h, so each hop is an UNWEIGHTED neighbor sum:
//   g0 = dinv .* (x W^T)
//   g1 = dinv^2 .* (g0 + sum_{dst=n} g0[src])
//   out = dinv .* (g1 + sum_{dst=n} g1[src]) + b
//
// CSR build without global scans or random 4B scatters:
//   bucket_k : chunked counting-sort of edges into 782 dst-buckets (128 nodes
//              each) -> contiguous per-(chunk,bucket) runs, 1 atomic per run.
//   regroup_k: per bucket, LDS histogram + scan + scatter -> per-node runs,
//              written back IN-PLACE (coalesced); meta[node] = {beg, cnt}.
// GEMM (R6): register-tile 4x4 per thread. x-tile + W staged TRANSPOSED in
//   padded LDS (stride 68 -> conflict-free ds_read_b128); per k: 2 LDS b128 +
//   16 float4-FMAs. No readlane (R5: 1 FLOP/instr ceiling), no W remat (R4).
// Hops: one wave per node, register accumulation, 100k independent waves.
//
// ws: gcur[1024] | pairs/ent[1024*2048] (8MB, in-place) | meta int2[N] | g1[N*64]

#define DF 64
#define BSHIFT 7
#define BNODES 128                 // nodes per bucket
#define NBP 1024                   // padded bucket count (used: ceil(N/128)=782)
#define CAP 2048                   // entries per bucket region (avg 1279, +21 sigma)
#define CHUNK 8192                 // edges per binning chunk
#define GS 68                      // padded LDS stride (floats), 16B-aligned, bank-spread

// ---- init bucket cursors ----
__global__ __launch_bounds__(256) void zero_k(int* __restrict__ gcur) {
    int i = blockIdx.x * 256 + threadIdx.x;
    if (i < NBP) gcur[i] = i * CAP;
}

// ---- chunked counting-sort of edges into dst-buckets ----
__global__ __launch_bounds__(256) void bucket_k(const int* __restrict__ src,
                                                const int* __restrict__ dst,
                                                int* gcur,
                                                unsigned* __restrict__ pairs, int ne) {
    __shared__ int bcnt[NBP];
    __shared__ int bofs[NBP];      // exclusive offsets, then running cursor
    __shared__ int gshift[NBP];    // global_base - local_exclusive_base
    __shared__ int stmp[256];
    int t = threadIdx.x;
    int e0 = blockIdx.x * CHUNK;
    int ecnt = min(CHUNK, ne - e0);

    for (int b = t; b < NBP; b += 256) bcnt[b] = 0;
    __syncthreads();

    // pass 1: per-bucket counts
    for (int i = t; i < ecnt; i += 256) {
        int d = dst[e0 + i];
        atomicAdd(&bcnt[d >> BSHIFT], 1);
    }
    __syncthreads();

    // block-exclusive scan over NBP=1024 counts (thread t owns 4t..4t+3)
    int b4 = t * 4;
    int c0 = bcnt[b4], c1 = bcnt[b4 + 1], c2 = bcnt[b4 + 2], c3 = bcnt[b4 + 3];
    int tsum = c0 + c1 + c2 + c3;
    stmp[t] = tsum;
    __syncthreads();
    for (int off = 1; off < 256; off <<= 1) {
        int v = stmp[t];
        int u = (t >= off) ? stmp[t - off] : 0;
        __syncthreads();
        stmp[t] = v + u;
        __syncthreads();
    }
    int ex = stmp[t] - tsum;
    int e1 = ex + c0, e2 = e1 + c1, e3 = e2 + c2;
    bofs[b4] = ex; bofs[b4 + 1] = e1; bofs[b4 + 2] = e2; bofs[b4 + 3] = e3;
    if (c0 > 0) gshift[b4]     = atomicAdd(&gcur[b4],     c0) - ex;
    if (c1 > 0) gshift[b4 + 1] = atomicAdd(&gcur[b4 + 1], c1) - e1;
    if (c2 > 0) gshift[b4 + 2] = atomicAdd(&gcur[b4 + 2], c2) - e2;
    if (c3 > 0) gshift[b4 + 3] = atomicAdd(&gcur[b4 + 3], c3) - e3;
    __syncthreads();

    // pass 2: scatter packed entries (row7|src17) into contiguous runs
    for (int i = t; i < ecnt; i += 256) {
        int d = dst[e0 + i], s = src[e0 + i];
        int b = d >> BSHIFT;
        int lp = atomicAdd(&bofs[b], 1);
        pairs[gshift[b] + lp] = ((unsigned)(d & (BNODES - 1)) << 17) | (unsigned)s;
    }
}

// ---- per-bucket regroup: node-sorted entries (in-place) + meta{beg,cnt} ----
__global__ __launch_bounds__(256) void regroup_k(const int* __restrict__ gcur,
                                                 unsigned* pairs,   // in: packed, out: ent
                                                 int2* __restrict__ meta, int n) {
    __shared__ int hist[BNODES];
    __shared__ int cur[BNODES];
    __shared__ int stage[CAP];
    int t = threadIdx.x, b = blockIdx.x;
    int base = b * CAP;
    int size = min(gcur[b] - base, CAP);

    if (t < BNODES) hist[t] = 0;
    __syncthreads();

    for (int i = t; i < size; i += 256)
        atomicAdd(&hist[pairs[base + i] >> 17], 1);
    __syncthreads();

    int cnt = (t < BNODES) ? hist[t] : 0;
    // Hillis-Steele inclusive scan over hist[0..127]
    for (int off = 1; off < BNODES; off <<= 1) {
        int u = (t < BNODES && t >= off) ? hist[t - off] : 0;
        __syncthreads();
        if (t < BNODES) hist[t] += u;
        __syncthreads();
    }
    if (t < BNODES) {
        int ex = hist[t] - cnt;
        cur[t] = ex;
        int node = (b << BSHIFT) + t;
        if (node < n) meta[node] = make_int2(base + ex, cnt);
    }
    __syncthreads();

    // scatter into LDS stage grouped by node
    for (int i = t; i < size; i += 256) {
        unsigned p = pairs[base + i];
        int pos = atomicAdd(&cur[p >> 17], 1);
        stage[pos] = (int)(p & 0x1FFFF);
    }
    __syncthreads();

    // coalesced write-back over the same region (block exclusively owns it)
    for (int i = t; i < size; i += 256)
        pairs[base + i] = (unsigned)stage[i];
}

// ---- g0 = dinv .* (x W^T): register-tile 4x4, transposed LDS staging ----
// Block = 64-row tile. xt[k*GS+r] = x[row0+r][k]; wt[k*GS+j] = W[j][k].
// Thread (tr,tc,wv): rows 4tr..4tr+3, cols wv*16+4tc..+3.
// Per k: 2 conflict-free ds_read_b128 + 16 FMA.
__global__ __launch_bounds__(256) void gemm_xw(const float* __restrict__ x,
                                               const float* __restrict__ Wm,
                                               const int2* __restrict__ meta,
                                               float* __restrict__ g0, int nrows) {
    __shared__ float xt[64 * GS];   // 17.4 KB
    __shared__ float wt[64 * GS];   // 17.4 KB
    int t = threadIdx.x;
    const float4* X4 = (const float4*)x;
    const float4* W4 = (const float4*)Wm;

    // staging map: j/r = t>>2 (16 consecutive 4-lane groups), k4 = (t&3)+4p
    int sr = t >> 2;            // 0..63
    int sk = t & 3;             // 0..3
    int row0 = blockIdx.x * 64;
#pragma unroll
    for (int p = 0; p < 4; ++p) {
        int k4 = sk + 4 * p;
        // W: fully coalesced read, conflict-free transposed write
        float4 wv = W4[sr * 16 + k4];
        wt[(4 * k4 + 0) * GS + sr] = wv.x;
        wt[(4 * k4 + 1) * GS + sr] = wv.y;
        wt[(4 * k4 + 2) * GS + sr] = wv.z;
        wt[(4 * k4 + 3) * GS + sr] = wv.w;
        // x tile
        int gr = row0 + sr;
        float4 xv = X4[(gr < nrows ? gr : 0) * 16 + k4];
        xt[(4 * k4 + 0) * GS + sr] = xv.x;
        xt[(4 * k4 + 1) * GS + sr] = xv.y;
        xt[(4 * k4 + 2) * GS + sr] = xv.z;
        xt[(4 * k4 + 3) * GS + sr] = xv.w;
    }
    __syncthreads();

    int lane = t & 63;
    int wv_ = t >> 6;           // wave 0..3
    int tr = lane & 15;         // row group 0..15
    int tc = lane >> 4;         // col group 0..3
    int cb = wv_ * 16 + tc * 4; // column base
    int xoff = 4 * tr;

    float4 acc[4];
#pragma unroll
    for (int i = 0; i < 4; ++i) acc[i] = make_float4(0.f, 0.f, 0.f, 0.f);

#pragma unroll 8
    for (int k = 0; k < 64; ++k) {
        float4 xv = *(const float4*)&xt[k * GS + xoff];
        float4 wq = *(const float4*)&wt[k * GS + cb];
        acc[0].x = fmaf(xv.x, wq.x, acc[0].x);
        acc[0].y = fmaf(xv.x, wq.y, acc[0].y);
        acc[0].z = fmaf(xv.x, wq.z, acc[0].z);
        acc[0].w = fmaf(xv.x, wq.w, acc[0].w);
        acc[1].x = fmaf(xv.y, wq.x, acc[1].x);
        acc[1].y = fmaf(xv.y, wq.y, acc[1].y);
        acc[1].z = fmaf(xv.y, wq.z, acc[1].z);
        acc[1].w = fmaf(xv.y, wq.w, acc[1].w);
        acc[2].x = fmaf(xv.z, wq.x, acc[2].x);
        acc[2].y = fmaf(xv.z, wq.y, acc[2].y);
        acc[2].z = fmaf(xv.z, wq.z, acc[2].z);
        acc[2].w = fmaf(xv.z, wq.w, acc[2].w);
        acc[3].x = fmaf(xv.w, wq.x, acc[3].x);
        acc[3].y = fmaf(xv.w, wq.y, acc[3].y);
        acc[3].z = fmaf(xv.w, wq.z, acc[3].z);
        acc[3].w = fmaf(xv.w, wq.w, acc[3].w);
    }

    float4* G4 = (float4*)g0;
#pragma unroll
    for (int i = 0; i < 4; ++i) {
        int gr = row0 + 4 * tr + i;
        if (gr < nrows) {
            float dv = rsqrtf((float)(1 + meta[gr].y));
            float4 a = acc[i];
            G4[gr * 16 + wv_ * 4 + tc] =
                make_float4(a.x * dv, a.y * dv, a.z * dv, a.w * dv);
        }
    }
}

// ---- gather hop: one wave per node, register accumulation, 8-deep ILP ----
// MODE 0: out = dinv^2*(self+acc)      MODE 1: out = dinv*(self+acc)+bias
template <int MODE>
__global__ __launch_bounds__(256) void gather_k(const int2* __restrict__ meta,
                                                const unsigned* __restrict__ ent,
                                                const float* __restrict__ gin,
                                                const float* __restrict__ bias,
                                                float* __restrict__ out, int n) {
    int lane = threadIdx.x & 63;
    int wid = (blockIdx.x * blockDim.x + threadIdx.x) >> 6;
    wid = __builtin_amdgcn_readfirstlane(wid);   // wave-uniform -> scalar loads
    if (wid >= n) return;

    int2 m = meta[wid];
    int beg = m.x, cnt = m.y;
    float dv = rsqrtf((float)(1 + cnt));

    float a0 = gin[wid * DF + lane];  // self-loop term
    float a1 = 0.f, a2 = 0.f, a3 = 0.f, a4 = 0.f, a5 = 0.f, a6 = 0.f, a7 = 0.f;

    int i = beg, end = beg + cnt;
    for (; i + 7 < end; i += 8) {     // 8 independent chains
        int s0 = ent[i + 0], s1 = ent[i + 1], s2 = ent[i + 2], s3 = ent[i + 3];
        int s4 = ent[i + 4], s5 = ent[i + 5], s6 = ent[i + 6], s7 = ent[i + 7];
        a0 += gin[s0 * DF + lane];
        a1 += gin[s1 * DF + lane];
        a2 += gin[s2 * DF + lane];
        a3 += gin[s3 * DF + lane];
        a4 += gin[s4 * DF + lane];
        a5 += gin[s5 * DF + lane];
        a6 += gin[s6 * DF + lane];
        a7 += gin[s7 * DF + lane];
    }
    for (; i + 3 < end; i += 4) {
        int s0 = ent[i + 0], s1 = ent[i + 1], s2 = ent[i + 2], s3 = ent[i + 3];
        a0 += gin[s0 * DF + lane];
        a1 += gin[s1 * DF + lane];
        a2 += gin[s2 * DF + lane];
        a3 += gin[s3 * DF + lane];
    }
    for (; i < end; ++i) a0 += gin[ent[i] * DF + lane];

    float acc = ((a0 + a1) + (a2 + a3)) + ((a4 + a5) + (a6 + a7));
    if (MODE == 0)
        out[wid * DF + lane] = dv * dv * acc;
    else
        out[wid * DF + lane] = fmaf(dv, acc, bias[lane]);
}

extern "C" void kernel_launch(void* const* d_in, const int* in_sizes, int n_in,
                              void* d_out, int out_size, void* d_ws, size_t ws_size,
                              hipStream_t stream) {
    const float* x  = (const float*)d_in[0];
    const int*   ei = (const int*)d_in[1];
    const float* Wm = (const float*)d_in[2];
    const float* b  = (const float*)d_in[3];

    const int N = in_sizes[0] / DF;   // 100000
    const int E = in_sizes[1] / 2;    // 1000000
    const int* src = ei;
    const int* dst = ei + E;

    int*      gcur  = (int*)d_ws;                    // NBP
    unsigned* pairs = (unsigned*)(gcur + NBP);       // NBP*CAP (8MB), becomes ent
    int2*     meta  = (int2*)(pairs + NBP * CAP);    // N
    float*    g1    = (float*)(meta + N);            // N*DF
    float*    g0    = (float*)d_out;                 // reuse output buffer

    int gC = (E + CHUNK - 1) / CHUNK;                // 123 chunks
    int NB = (N + BNODES - 1) / BNODES;              // 782 buckets
    int gG = (N * DF + 255) / 256;                   // one wave per node
    int gM = (N + 63) / 64;                          // 64-row GEMM tiles

    zero_k<<<4, 256, 0, stream>>>(gcur);
    bucket_k<<<gC, 256, 0, stream>>>(src, dst, gcur, pairs, E);
    regroup_k<<<NB, 256, 0, stream>>>(gcur, pairs, meta, N);
    gemm_xw<<<gM, 256, 0, stream>>>(x, Wm, meta, g0, N);
    gather_k<0><<<gG, 256, 0, stream>>>(meta, pairs, g0, nullptr, g1, N);
    gather_k<1><<<gG, 256, 0, stream>>>(meta, pairs, g1, b, g0, N);
}